// Round 1
// baseline (528.714 us; speedup 1.0000x reference)
//
#include <hip/hip_runtime.h>

#define N_NODES  100000
#define N_EDGES  1200000
#define N_GRAPHS 1024
#define F        64
#define BN_EPS   1e-5f

// ---------------------------------------------------------------------------
// Kernel 1: edge scatter. One wave (64 lanes) per edge; lane = feature.
// atomicAdd agg[dst][lane] += feats[src][lane]; lane0 counts degree.
// ---------------------------------------------------------------------------
__global__ __launch_bounds__(256) void edge_scatter(
    const float* __restrict__ feats, const int* __restrict__ src,
    const int* __restrict__ dst, float* __restrict__ agg,
    float* __restrict__ deg) {
  int lane = threadIdx.x & 63;
  int wid  = (blockIdx.x * blockDim.x + threadIdx.x) >> 6;
  int nw   = (gridDim.x * blockDim.x) >> 6;
  for (int e = wid; e < N_EDGES; e += nw) {
    int s = src[e];
    int d = dst[e];
    float v = feats[(size_t)s * F + lane];
    atomicAdd(&agg[(size_t)d * F + lane], v);
    if (lane == 0) atomicAdd(&deg[d], 1.0f);
  }
}

// ---------------------------------------------------------------------------
// Kernel 2: node update. h = relu(feats@Wself + (agg/max(deg,1))@Wneigh + b).
// One wave per node; lane = output feature. Weight columns cached in VGPRs
// (128 regs/lane), per-node broadcasts via v_readlane -> pure VALU inner loop
// (no LDS traffic). Writes h in-place over agg.
// ---------------------------------------------------------------------------
__global__ __launch_bounds__(256) void node_update(
    const float* __restrict__ feats, const float* __restrict__ Wself,
    const float* __restrict__ Wneigh, const float* __restrict__ bneigh,
    const float* __restrict__ deg, float* __restrict__ aggh) {
  int lane = threadIdx.x & 63;
  int wid  = (blockIdx.x * blockDim.x + threadIdx.x) >> 6;
  int nw   = (gridDim.x * blockDim.x) >> 6;

  float ws[F], wn[F];
#pragma unroll
  for (int i = 0; i < F; i++) {
    ws[i] = Wself[i * F + lane];   // coalesced: column `lane`
    wn[i] = Wneigh[i * F + lane];
  }
  float bias = bneigh[lane];

  for (int n = wid; n < N_NODES; n += nw) {   // uniform trip count -> no divergence
    float f = feats[(size_t)n * F + lane];
    float a = aggh[(size_t)n * F + lane];
    float inv = 1.0f / fmaxf(deg[n], 1.0f);
    float m = a * inv;
    int fb = __float_as_int(f);
    int mb = __float_as_int(m);
    float acc = bias;
#pragma unroll
    for (int i = 0; i < F; i++) {
      float fi = __int_as_float(__builtin_amdgcn_readlane(fb, i));
      float mi = __int_as_float(__builtin_amdgcn_readlane(mb, i));
      acc += fi * ws[i];
      acc += mi * wn[i];
    }
    aggh[(size_t)n * F + lane] = fmaxf(acc, 0.0f);
  }
}

// ---------------------------------------------------------------------------
// Kernel 3: per-graph max readout. graph_ids are SORTED, so block g binary-
// searches its start and scans its contiguous run. No atomics. h >= 0 after
// relu, so identity 0 is safe (empty graphs ~impossible: P ~ e^-97).
// ---------------------------------------------------------------------------
__global__ __launch_bounds__(64) void seg_max(
    const float* __restrict__ h, const int* __restrict__ gids,
    float* __restrict__ hg) {
  int g = blockIdx.x;
  int lane = threadIdx.x;
  int lo = 0, hi = N_NODES;
  while (lo < hi) {                 // lower_bound(gids, g) — uniform loop
    int mid = (lo + hi) >> 1;
    if (gids[mid] < g) lo = mid + 1; else hi = mid;
  }
  float m = 0.0f;
  for (int n = lo; n < N_NODES && gids[n] == g; n++)
    m = fmaxf(m, h[(size_t)n * F + lane]);
  hg[(size_t)g * F + lane] = m;
}

// ---------------------------------------------------------------------------
// Kernel 4: MLP head with eval-mode BN. One block (128 threads) per graph.
// ---------------------------------------------------------------------------
__global__ __launch_bounds__(128) void mlp(
    const float* __restrict__ hg,
    const float* __restrict__ W1, const float* __restrict__ b1,
    const float* __restrict__ g1, const float* __restrict__ be1,
    const float* __restrict__ rm1, const float* __restrict__ rv1,
    const float* __restrict__ W2, const float* __restrict__ b2,
    const float* __restrict__ g2, const float* __restrict__ be2,
    const float* __restrict__ rm2, const float* __restrict__ rv2,
    const float* __restrict__ W3, const float* __restrict__ b3,
    float* __restrict__ out) {
  __shared__ float s0[64];
  __shared__ float s1[128];
  __shared__ float s2[64];
  int g = blockIdx.x;
  int t = threadIdx.x;

  if (t < 64) s0[t] = hg[(size_t)g * F + t];
  __syncthreads();

  // layer 1: 64 -> 128, relu, BN
  {
    float acc = b1[t];
    for (int i = 0; i < 64; i++) acc += s0[i] * W1[i * 128 + t];
    acc = fmaxf(acc, 0.0f);
    acc = (acc - rm1[t]) * (1.0f / sqrtf(rv1[t] + BN_EPS)) * g1[t] + be1[t];
    s1[t] = acc;
  }
  __syncthreads();

  // layer 2: 128 -> 64, relu, BN
  if (t < 64) {
    float acc = b2[t];
    for (int i = 0; i < 128; i++) acc += s1[i] * W2[i * 64 + t];
    acc = fmaxf(acc, 0.0f);
    acc = (acc - rm2[t]) * (1.0f / sqrtf(rv2[t] + BN_EPS)) * g2[t] + be2[t];
    s2[t] = acc;
  }
  __syncthreads();

  // layer 3: 64 -> 1, wave-0 reduction
  if (t < 64) {
    float p = s2[t] * W3[t];
    for (int off = 32; off > 0; off >>= 1) p += __shfl_down(p, off);
    if (t == 0) out[g] = p + b3[0];
  }
}

// ---------------------------------------------------------------------------
extern "C" void kernel_launch(void* const* d_in, const int* in_sizes, int n_in,
                              void* d_out, int out_size, void* d_ws, size_t ws_size,
                              hipStream_t stream) {
  const float* feats  = (const float*)d_in[0];
  const int*   src    = (const int*)d_in[1];
  const int*   dst    = (const int*)d_in[2];
  const int*   gids   = (const int*)d_in[3];
  const float* Wself  = (const float*)d_in[4];
  const float* Wneigh = (const float*)d_in[5];
  const float* bneigh = (const float*)d_in[6];
  const float* W1  = (const float*)d_in[7];
  const float* b1  = (const float*)d_in[8];
  const float* g1  = (const float*)d_in[9];
  const float* be1 = (const float*)d_in[10];
  const float* rm1 = (const float*)d_in[11];
  const float* rv1 = (const float*)d_in[12];
  const float* W2  = (const float*)d_in[13];
  const float* b2  = (const float*)d_in[14];
  const float* g2  = (const float*)d_in[15];
  const float* be2 = (const float*)d_in[16];
  const float* rm2 = (const float*)d_in[17];
  const float* rv2 = (const float*)d_in[18];
  const float* W3  = (const float*)d_in[19];
  const float* b3  = (const float*)d_in[20];

  float* agg = (float*)d_ws;                        // N_NODES*F floats (also h, in-place)
  float* deg = agg + (size_t)N_NODES * F;           // N_NODES floats
  float* hg  = deg + N_NODES;                       // N_GRAPHS*F floats

  // zero agg + deg (ws is poisoned 0xAA before every call)
  hipMemsetAsync(agg, 0, ((size_t)N_NODES * F + N_NODES) * sizeof(float), stream);

  edge_scatter<<<8192, 256, 0, stream>>>(feats, src, dst, agg, deg);
  node_update<<<1024, 256, 0, stream>>>(feats, Wself, Wneigh, bneigh, deg, agg);
  seg_max<<<N_GRAPHS, 64, 0, stream>>>(agg, gids, hg);
  mlp<<<N_GRAPHS, 128, 0, stream>>>(hg, W1, b1, g1, be1, rm1, rv1,
                                    W2, b2, g2, be2, rm2, rv2, W3, b3,
                                    (float*)d_out);
}

// Round 2
// 472.071 us; speedup vs baseline: 1.1200x; 1.1200x over previous
//
#include <hip/hip_runtime.h>

#define N_NODES  100000
#define N_EDGES  1200000
#define N_GRAPHS 1024
#define F        64
#define BN_EPS   1e-5f
#define NB_SCAN  ((N_NODES + 1023) / 1024)   // 98 scan blocks, 1024 elems each

// ---------------------------------------------------------------------------
// CSR build step 1: in-degree histogram (int atomics, 400KB target -> cheap)
// ---------------------------------------------------------------------------
__global__ __launch_bounds__(256) void hist(const int* __restrict__ dst,
                                            int* __restrict__ cnt) {
  int i = blockIdx.x * blockDim.x + threadIdx.x;
  int n = gridDim.x * blockDim.x;
  for (int e = i; e < N_EDGES; e += n) atomicAdd(&cnt[dst[e]], 1);
}

// ---------------------------------------------------------------------------
// CSR build step 2a: per-block exclusive scan (1024 elems/block of 256 thr)
// ---------------------------------------------------------------------------
__global__ __launch_bounds__(256) void scan_local(const int* __restrict__ cnt,
                                                  int* __restrict__ rs,
                                                  int* __restrict__ bsum) {
  __shared__ int s[256];
  int b = blockIdx.x, t = threadIdx.x;
  int base = b * 1024 + t * 4;
  int c0 = (base + 0 < N_NODES) ? cnt[base + 0] : 0;
  int c1 = (base + 1 < N_NODES) ? cnt[base + 1] : 0;
  int c2 = (base + 2 < N_NODES) ? cnt[base + 2] : 0;
  int c3 = (base + 3 < N_NODES) ? cnt[base + 3] : 0;
  int tsum = c0 + c1 + c2 + c3;
  s[t] = tsum;
  __syncthreads();
  for (int off = 1; off < 256; off <<= 1) {        // Hillis-Steele inclusive
    int v = (t >= off) ? s[t - off] : 0;
    __syncthreads();
    s[t] += v;
    __syncthreads();
  }
  int excl = s[t] - tsum;                          // exclusive within block
  if (t == 255) bsum[b] = s[255];                  // block total
  if (base + 0 < N_NODES) rs[base + 0] = excl;
  if (base + 1 < N_NODES) rs[base + 1] = excl + c0;
  if (base + 2 < N_NODES) rs[base + 2] = excl + c0 + c1;
  if (base + 3 < N_NODES) rs[base + 3] = excl + c0 + c1 + c2;
}

// step 2b: exclusive-scan the 98 block sums (serial: 98 iters is nothing)
__global__ void scan_sums(int* __restrict__ bsum) {
  if (threadIdx.x == 0) {
    int acc = 0;
    for (int i = 0; i < NB_SCAN; i++) { int v = bsum[i]; bsum[i] = acc; acc += v; }
  }
}

// step 2c: add block offsets; append rs[N_NODES] = N_EDGES
__global__ __launch_bounds__(256) void scan_add(int* __restrict__ rs,
                                                const int* __restrict__ bsum) {
  int i = blockIdx.x * blockDim.x + threadIdx.x;
  if (i < N_NODES) rs[i] += bsum[i >> 10];
  if (i == 0) rs[N_NODES] = N_EDGES;
}

// ---------------------------------------------------------------------------
// CSR build step 3: fill edge list grouped by dst
// ---------------------------------------------------------------------------
__global__ __launch_bounds__(256) void fill_csr(const int* __restrict__ src,
                                                const int* __restrict__ dst,
                                                const int* __restrict__ rs,
                                                int* __restrict__ cursor,
                                                int* __restrict__ eidx) {
  int i = blockIdx.x * blockDim.x + threadIdx.x;
  int n = gridDim.x * blockDim.x;
  for (int e = i; e < N_EDGES; e += n) {
    int d = dst[e];
    int pos = rs[d] + atomicAdd(&cursor[d], 1);
    eidx[pos] = src[e];
  }
}

// ---------------------------------------------------------------------------
// Fused: neighbor-mean gather + SAGE update + ReLU + per-graph max readout.
// One wave per node; lane = feature. Weights pinned in 128 VGPRs, per-node
// broadcasts via v_readlane (pure VALU matmul). Readout via int atomicMax on
// float bits (valid: h >= 0 after ReLU, IEEE order == int order for >= 0).
// ---------------------------------------------------------------------------
__global__ __launch_bounds__(256) void agg_update(
    const float* __restrict__ feats, const int* __restrict__ rs,
    const int* __restrict__ eidx, const float* __restrict__ Wself,
    const float* __restrict__ Wneigh, const float* __restrict__ bneigh,
    const int* __restrict__ gids, int* __restrict__ hgbits) {
  int lane = threadIdx.x & 63;
  int wid  = (blockIdx.x * blockDim.x + threadIdx.x) >> 6;
  int nw   = (gridDim.x * blockDim.x) >> 6;

  float wsv[F], wnv[F];
#pragma unroll
  for (int i = 0; i < F; i++) {
    wsv[i] = Wself[i * F + lane];
    wnv[i] = Wneigh[i * F + lane];
  }
  float bias = bneigh[lane];

  for (int n = wid; n < N_NODES; n += nw) {
    int r0 = rs[n], r1 = rs[n + 1];
    float sum = 0.0f;
    for (int base = r0; base < r1; base += 64) {   // chunks of <=64 neighbors
      int m = r1 - base; if (m > 64) m = 64;
      int myid = (lane < m) ? eidx[base + lane] : 0;
      for (int j = 0; j < m; j++) {
        int sid = __builtin_amdgcn_readlane(myid, j);
        sum += feats[(size_t)sid * F + lane];      // coalesced 256B row gather
      }
    }
    float inv  = 1.0f / fmaxf((float)(r1 - r0), 1.0f);
    float mean = sum * inv;
    float f    = feats[(size_t)n * F + lane];
    int fb = __float_as_int(f), mb = __float_as_int(mean);
    float acc = bias;
#pragma unroll
    for (int i = 0; i < F; i++) {
      acc += __int_as_float(__builtin_amdgcn_readlane(fb, i)) * wsv[i];
      acc += __int_as_float(__builtin_amdgcn_readlane(mb, i)) * wnv[i];
    }
    float h = fmaxf(acc, 0.0f);
    int g = gids[n];
    atomicMax(&hgbits[(size_t)g * F + lane], __float_as_int(h));
  }
}

// ---------------------------------------------------------------------------
// MLP head with eval-mode BN. One block (128 threads) per graph.
// ---------------------------------------------------------------------------
__global__ __launch_bounds__(128) void mlp(
    const float* __restrict__ hg,
    const float* __restrict__ W1, const float* __restrict__ b1,
    const float* __restrict__ g1, const float* __restrict__ be1,
    const float* __restrict__ rm1, const float* __restrict__ rv1,
    const float* __restrict__ W2, const float* __restrict__ b2,
    const float* __restrict__ g2, const float* __restrict__ be2,
    const float* __restrict__ rm2, const float* __restrict__ rv2,
    const float* __restrict__ W3, const float* __restrict__ b3,
    float* __restrict__ out) {
  __shared__ float s0[64];
  __shared__ float s1[128];
  __shared__ float s2[64];
  int g = blockIdx.x;
  int t = threadIdx.x;

  if (t < 64) s0[t] = hg[(size_t)g * F + t];
  __syncthreads();

  {
    float acc = b1[t];
    for (int i = 0; i < 64; i++) acc += s0[i] * W1[i * 128 + t];
    acc = fmaxf(acc, 0.0f);
    acc = (acc - rm1[t]) * (1.0f / sqrtf(rv1[t] + BN_EPS)) * g1[t] + be1[t];
    s1[t] = acc;
  }
  __syncthreads();

  if (t < 64) {
    float acc = b2[t];
    for (int i = 0; i < 128; i++) acc += s1[i] * W2[i * 64 + t];
    acc = fmaxf(acc, 0.0f);
    acc = (acc - rm2[t]) * (1.0f / sqrtf(rv2[t] + BN_EPS)) * g2[t] + be2[t];
    s2[t] = acc;
  }
  __syncthreads();

  if (t < 64) {
    float p = s2[t] * W3[t];
    for (int off = 32; off > 0; off >>= 1) p += __shfl_down(p, off);
    if (t == 0) out[g] = p + b3[0];
  }
}

// ---------------------------------------------------------------------------
extern "C" void kernel_launch(void* const* d_in, const int* in_sizes, int n_in,
                              void* d_out, int out_size, void* d_ws, size_t ws_size,
                              hipStream_t stream) {
  const float* feats  = (const float*)d_in[0];
  const int*   src    = (const int*)d_in[1];
  const int*   dst    = (const int*)d_in[2];
  const int*   gids   = (const int*)d_in[3];
  const float* Wself  = (const float*)d_in[4];
  const float* Wneigh = (const float*)d_in[5];
  const float* bneigh = (const float*)d_in[6];
  const float* W1  = (const float*)d_in[7];
  const float* b1  = (const float*)d_in[8];
  const float* g1  = (const float*)d_in[9];
  const float* be1 = (const float*)d_in[10];
  const float* rm1 = (const float*)d_in[11];
  const float* rv1 = (const float*)d_in[12];
  const float* W2  = (const float*)d_in[13];
  const float* b2  = (const float*)d_in[14];
  const float* g2  = (const float*)d_in[15];
  const float* be2 = (const float*)d_in[16];
  const float* rm2 = (const float*)d_in[17];
  const float* rv2 = (const float*)d_in[18];
  const float* W3  = (const float*)d_in[19];
  const float* b3  = (const float*)d_in[20];

  // ws layout: rs | cnt | cursor | hgbits | bsum | eidx
  int* rs     = (int*)d_ws;                         // N_NODES+1
  int* cnt    = rs + (N_NODES + 1);                 // N_NODES  } zeroed
  int* cursor = cnt + N_NODES;                      // N_NODES  } zeroed
  int* hgbits = cursor + N_NODES;                   // N_GRAPHS*F } zeroed
  int* bsum   = hgbits + (size_t)N_GRAPHS * F;      // NB_SCAN
  int* eidx   = bsum + NB_SCAN;                     // N_EDGES

  // zero cnt + cursor + hgbits in one shot (contiguous)
  hipMemsetAsync(cnt, 0, (2 * (size_t)N_NODES + (size_t)N_GRAPHS * F) * sizeof(int),
                 stream);

  hist<<<1024, 256, 0, stream>>>(dst, cnt);
  scan_local<<<NB_SCAN, 256, 0, stream>>>(cnt, rs, bsum);
  scan_sums<<<1, 64, 0, stream>>>(bsum);
  scan_add<<<(N_NODES + 255) / 256, 256, 0, stream>>>(rs, bsum);
  fill_csr<<<1024, 256, 0, stream>>>(src, dst, rs, cursor, eidx);
  agg_update<<<2048, 256, 0, stream>>>(feats, rs, eidx, Wself, Wneigh, bneigh,
                                       gids, hgbits);
  mlp<<<N_GRAPHS, 128, 0, stream>>>((const float*)hgbits,
                                    W1, b1, g1, be1, rm1, rv1,
                                    W2, b2, g2, be2, rm2, rv2, W3, b3,
                                    (float*)d_out);
}

// Round 3
// 382.661 us; speedup vs baseline: 1.3817x; 1.2337x over previous
//
#include <hip/hip_runtime.h>

#define N_NODES  100000
#define N_EDGES  1200000
#define N_GRAPHS 1024
#define F        64
#define BN_EPS   1e-5f
#define NB_SCAN  ((N_NODES + 1023) / 1024)   // 98 scan blocks, 1024 elems each

// ---------------------------------------------------------------------------
// CSR build step 1: in-degree histogram
// ---------------------------------------------------------------------------
__global__ __launch_bounds__(256) void hist(const int* __restrict__ dst,
                                            int* __restrict__ cnt) {
  int i = blockIdx.x * blockDim.x + threadIdx.x;
  int n = gridDim.x * blockDim.x;
  for (int e = i; e < N_EDGES; e += n) atomicAdd(&cnt[dst[e]], 1);
}

// ---------------------------------------------------------------------------
// CSR build step 2a: per-block exclusive scan (1024 elems/block)
// ---------------------------------------------------------------------------
__global__ __launch_bounds__(256) void scan_local(const int* __restrict__ cnt,
                                                  int* __restrict__ rs,
                                                  int* __restrict__ bsum) {
  __shared__ int s[256];
  int b = blockIdx.x, t = threadIdx.x;
  int base = b * 1024 + t * 4;
  int c0 = (base + 0 < N_NODES) ? cnt[base + 0] : 0;
  int c1 = (base + 1 < N_NODES) ? cnt[base + 1] : 0;
  int c2 = (base + 2 < N_NODES) ? cnt[base + 2] : 0;
  int c3 = (base + 3 < N_NODES) ? cnt[base + 3] : 0;
  int tsum = c0 + c1 + c2 + c3;
  s[t] = tsum;
  __syncthreads();
  for (int off = 1; off < 256; off <<= 1) {
    int v = (t >= off) ? s[t - off] : 0;
    __syncthreads();
    s[t] += v;
    __syncthreads();
  }
  int excl = s[t] - tsum;
  if (t == 255) bsum[b] = s[255];
  if (base + 0 < N_NODES) rs[base + 0] = excl;
  if (base + 1 < N_NODES) rs[base + 1] = excl + c0;
  if (base + 2 < N_NODES) rs[base + 2] = excl + c0 + c1;
  if (base + 3 < N_NODES) rs[base + 3] = excl + c0 + c1 + c2;
}

// step 2b: wave-parallel shuffle scan of 98 block sums (2 elems/lane)
__global__ __launch_bounds__(64) void scan_sums(int* __restrict__ bsum) {
  int l = threadIdx.x;
  int v0 = (2 * l     < NB_SCAN) ? bsum[2 * l]     : 0;
  int v1 = (2 * l + 1 < NB_SCAN) ? bsum[2 * l + 1] : 0;
  int s = v0 + v1;
  for (int off = 1; off < 64; off <<= 1) {
    int t = __shfl_up(s, off);
    if (l >= off) s += t;
  }
  int excl = s - (v0 + v1);
  if (2 * l     < NB_SCAN) bsum[2 * l]     = excl;
  if (2 * l + 1 < NB_SCAN) bsum[2 * l + 1] = excl + v0;
}

// step 2c: add block offsets; init cursor = rs; append rs[N_NODES]
__global__ __launch_bounds__(256) void scan_add(int* __restrict__ rs,
                                                int* __restrict__ cursor,
                                                const int* __restrict__ bsum) {
  int i = blockIdx.x * blockDim.x + threadIdx.x;
  if (i < N_NODES) {
    int v = rs[i] + bsum[i >> 10];
    rs[i] = v;
    cursor[i] = v;
  }
  if (i == 0) rs[N_NODES] = N_EDGES;
}

// ---------------------------------------------------------------------------
// CSR build step 3: fill edge list grouped by dst (cursor pre-seeded with rs)
// ---------------------------------------------------------------------------
__global__ __launch_bounds__(256) void fill_csr(const int* __restrict__ src,
                                                const int* __restrict__ dst,
                                                int* __restrict__ cursor,
                                                int* __restrict__ eidx) {
  int i = blockIdx.x * blockDim.x + threadIdx.x;
  int n = gridDim.x * blockDim.x;
  for (int e = i; e < N_EDGES; e += n) {
    int pos = atomicAdd(&cursor[dst[e]], 1);
    eidx[pos] = src[e];
  }
}

// ---------------------------------------------------------------------------
// Neighbor-mean gather. One wave per node-range; lane = 16*sub + f4:
// each float4 load instruction covers 4 neighbor rows (1KB/wave). Low VGPR
// -> high occupancy for latency hiding. Sub-partials combined by butterfly.
// ---------------------------------------------------------------------------
__global__ __launch_bounds__(256) void gather_mean(
    const float* __restrict__ feats, const int* __restrict__ rs,
    const int* __restrict__ eidx, float* __restrict__ mean) {
  int lane = threadIdx.x & 63;
  int wid  = (blockIdx.x * blockDim.x + threadIdx.x) >> 6;
  const int NW = (2048 * 256) >> 6;                 // 8192 waves
  const int per = (N_NODES + NW - 1) / NW;          // 13 nodes/wave
  int n0 = wid * per;
  int n1 = n0 + per; if (n1 > N_NODES) n1 = N_NODES;
  int fl  = lane & 15;                              // float4 index in row
  int sub = lane >> 4;                              // neighbor sub-slot 0..3

  for (int n = n0; n < n1; n++) {
    int r0 = rs[n], r1 = rs[n + 1];
    float sx = 0.f, sy = 0.f, sz = 0.f, sw = 0.f;
    for (int base = r0; base < r1; base += 64) {
      int m = r1 - base; if (m > 64) m = 64;
      int myid = (lane < m) ? eidx[base + lane] : 0;
      for (int j = 0; j < m; j += 4) {
        int sid = __shfl(myid, j + sub);            // j+sub <= 63 always
        const float4 v =
            *(const float4*)(feats + (size_t)sid * F + 4 * fl);
        if (j + sub < m) { sx += v.x; sy += v.y; sz += v.z; sw += v.w; }
      }
    }
    // combine the 4 sub-slot partials (xor 16, 32)
    sx += __shfl_xor(sx, 16); sy += __shfl_xor(sy, 16);
    sz += __shfl_xor(sz, 16); sw += __shfl_xor(sw, 16);
    sx += __shfl_xor(sx, 32); sy += __shfl_xor(sy, 32);
    sz += __shfl_xor(sz, 32); sw += __shfl_xor(sw, 32);
    float inv = 1.0f / fmaxf((float)(r1 - r0), 1.0f);
    if (sub == 0) {
      float4 mv = {sx * inv, sy * inv, sz * inv, sw * inv};
      *(float4*)(mean + (size_t)n * F + 4 * fl) = mv;
    }
  }
}

// ---------------------------------------------------------------------------
// SAGE update + ReLU + per-graph max. Weights pinned in 128 VGPRs
// (launch_bounds(256,2) grants the 256-VGPR budget). Contiguous node range
// per wave -> one atomicMax flush per (wave, graph) boundary (~3k total).
// ---------------------------------------------------------------------------
__global__ __launch_bounds__(256, 2) void node_out(
    const float* __restrict__ feats, const float* __restrict__ mean,
    const float* __restrict__ Wself, const float* __restrict__ Wneigh,
    const float* __restrict__ bneigh, const int* __restrict__ gids,
    int* __restrict__ hgbits) {
  int lane = threadIdx.x & 63;
  int wid  = (blockIdx.x * blockDim.x + threadIdx.x) >> 6;
  const int NW = (512 * 256) >> 6;                  // 2048 waves
  const int per = (N_NODES + NW - 1) / NW;          // 49 nodes/wave
  int n0 = wid * per;
  int n1 = n0 + per; if (n1 > N_NODES) n1 = N_NODES;
  if (n0 >= n1) return;

  float wsv[F], wnv[F];
#pragma unroll
  for (int i = 0; i < F; i++) {
    wsv[i] = Wself[i * F + lane];
    wnv[i] = Wneigh[i * F + lane];
  }
  float bias = bneigh[lane];

  int curg = gids[n0];
  float gmax = 0.0f;
  for (int n = n0; n < n1; n++) {
    int g = gids[n];                                // wave-uniform
    if (g != curg) {
      atomicMax(&hgbits[(size_t)curg * F + lane], __float_as_int(gmax));
      curg = g; gmax = 0.0f;
    }
    float f = feats[(size_t)n * F + lane];
    float m = mean[(size_t)n * F + lane];
    int fb = __float_as_int(f), mb = __float_as_int(m);
    float acc = bias;
#pragma unroll
    for (int i = 0; i < F; i++) {
      acc += __int_as_float(__builtin_amdgcn_readlane(fb, i)) * wsv[i];
      acc += __int_as_float(__builtin_amdgcn_readlane(mb, i)) * wnv[i];
    }
    gmax = fmaxf(gmax, fmaxf(acc, 0.0f));
  }
  atomicMax(&hgbits[(size_t)curg * F + lane], __float_as_int(gmax));
}

// ---------------------------------------------------------------------------
// MLP head: weights staged in LDS once, 8 graphs per block (128 blocks).
// BN folded to scale/shift.
// ---------------------------------------------------------------------------
#define GPB 8
__global__ __launch_bounds__(128) void mlp(
    const float* __restrict__ hg,
    const float* __restrict__ W1, const float* __restrict__ b1,
    const float* __restrict__ g1, const float* __restrict__ be1,
    const float* __restrict__ rm1, const float* __restrict__ rv1,
    const float* __restrict__ W2, const float* __restrict__ b2,
    const float* __restrict__ g2, const float* __restrict__ be2,
    const float* __restrict__ rm2, const float* __restrict__ rv2,
    const float* __restrict__ W3, const float* __restrict__ b3,
    float* __restrict__ out) {
  __shared__ float W1s[64 * 128];
  __shared__ float W2s[128 * 64];
  __shared__ float W3s[64];
  __shared__ float sc1[128], sh1[128], b1s[128];
  __shared__ float sc2[64],  sh2[64],  b2s[64];
  __shared__ float s0[64], s1[128], s2[64];
  int t = threadIdx.x;

  for (int i = t; i < 64 * 128; i += 128) W1s[i] = W1[i];
  for (int i = t; i < 128 * 64; i += 128) W2s[i] = W2[i];
  if (t < 64) W3s[t] = W3[t];
  {
    float iv = rsqrtf(rv1[t] + BN_EPS);
    float sc = g1[t] * iv;
    sc1[t] = sc; sh1[t] = be1[t] - rm1[t] * sc; b1s[t] = b1[t];
  }
  if (t < 64) {
    float iv = rsqrtf(rv2[t] + BN_EPS);
    float sc = g2[t] * iv;
    sc2[t] = sc; sh2[t] = be2[t] - rm2[t] * sc; b2s[t] = b2[t];
  }
  __syncthreads();

  for (int gg = 0; gg < GPB; gg++) {
    int g = blockIdx.x * GPB + gg;
    if (t < 64) s0[t] = hg[(size_t)g * F + t];
    __syncthreads();
    {
      float acc = b1s[t];
      for (int i = 0; i < 64; i++) acc += s0[i] * W1s[i * 128 + t];
      acc = fmaxf(acc, 0.0f);
      s1[t] = acc * sc1[t] + sh1[t];
    }
    __syncthreads();
    if (t < 64) {
      float acc = b2s[t];
      for (int i = 0; i < 128; i++) acc += s1[i] * W2s[i * 64 + t];
      acc = fmaxf(acc, 0.0f);
      s2[t] = acc * sc2[t] + sh2[t];
    }
    __syncthreads();
    if (t < 64) {
      float p = s2[t] * W3s[t];
      for (int off = 32; off > 0; off >>= 1) p += __shfl_down(p, off);
      if (t == 0) out[g] = p + b3[0];
    }
    __syncthreads();
  }
}

// ---------------------------------------------------------------------------
extern "C" void kernel_launch(void* const* d_in, const int* in_sizes, int n_in,
                              void* d_out, int out_size, void* d_ws, size_t ws_size,
                              hipStream_t stream) {
  const float* feats  = (const float*)d_in[0];
  const int*   src    = (const int*)d_in[1];
  const int*   dst    = (const int*)d_in[2];
  const int*   gids   = (const int*)d_in[3];
  const float* Wself  = (const float*)d_in[4];
  const float* Wneigh = (const float*)d_in[5];
  const float* bneigh = (const float*)d_in[6];
  const float* W1  = (const float*)d_in[7];
  const float* b1  = (const float*)d_in[8];
  const float* g1  = (const float*)d_in[9];
  const float* be1 = (const float*)d_in[10];
  const float* rm1 = (const float*)d_in[11];
  const float* rv1 = (const float*)d_in[12];
  const float* W2  = (const float*)d_in[13];
  const float* b2  = (const float*)d_in[14];
  const float* g2  = (const float*)d_in[15];
  const float* be2 = (const float*)d_in[16];
  const float* rm2 = (const float*)d_in[17];
  const float* rv2 = (const float*)d_in[18];
  const float* W3  = (const float*)d_in[19];
  const float* b3  = (const float*)d_in[20];

  // ws layout (mean first for 16B alignment of float4 stores)
  float* mean  = (float*)d_ws;                       // N_NODES*F
  int* cnt     = (int*)(mean + (size_t)N_NODES * F); // N_NODES    } zeroed
  int* hgbits  = cnt + N_NODES;                      // N_GRAPHS*F } zeroed
  int* rs      = hgbits + (size_t)N_GRAPHS * F;      // N_NODES+1
  int* cursor  = rs + (N_NODES + 1);                 // N_NODES
  int* bsum    = cursor + N_NODES;                   // NB_SCAN
  int* eidx    = bsum + NB_SCAN;                     // N_EDGES

  hipMemsetAsync(cnt, 0, ((size_t)N_NODES + (size_t)N_GRAPHS * F) * sizeof(int),
                 stream);

  hist<<<1024, 256, 0, stream>>>(dst, cnt);
  scan_local<<<NB_SCAN, 256, 0, stream>>>(cnt, rs, bsum);
  scan_sums<<<1, 64, 0, stream>>>(bsum);
  scan_add<<<(N_NODES + 255) / 256, 256, 0, stream>>>(rs, cursor, bsum);
  fill_csr<<<1024, 256, 0, stream>>>(src, dst, cursor, eidx);
  gather_mean<<<2048, 256, 0, stream>>>(feats, rs, eidx, mean);
  node_out<<<512, 256, 0, stream>>>(feats, mean, Wself, Wneigh, bneigh,
                                    gids, hgbits);
  mlp<<<N_GRAPHS / GPB, 128, 0, stream>>>((const float*)hgbits,
                                          W1, b1, g1, be1, rm1, rv1,
                                          W2, b2, g2, be2, rm2, rv2, W3, b3,
                                          (float*)d_out);
}